// Round 13
// baseline (13375.662 us; speedup 1.0000x reference)
//
#include <hip/hip_runtime.h>

// NeuralCDE: B=64,T=256,C=16,S=64,H=128. fp32 recursion (f16 decorrelates).
// R4 20.4ms stream-all; R5 62ms cross-block sync poison; R6-R12: indirect
// register-residency defeated 6x (caps/remat/reload; VGPR_Count pinned at 128
// = arch regs only). R13: EXPLICIT AGPR residency via literal
// v_accvgpr_write_b32/read_b32 inline asm — no load path to AGPRs exists, so
// reload/remat is impossible. Each thread holds W2 rows 2tid,2tid+1 (all 128
// cols) in 256 AGPRs. W0+W1 in LDS (padded strides). ZERO per-stage global
// traffic. 3-barrier stage (R11). y-states -> d_ws, parallel readout kernel.

typedef float float4v __attribute__((ext_vector_type(4)));
typedef float float2v __attribute__((ext_vector_type(2)));

__device__ __forceinline__ float dot4(float4v a, float4v b) {
  return a.x * b.x + a.y * b.y + a.z * b.z + a.w * b.w;
}

__device__ __forceinline__ float softplus_fast(float x) {
  float z = __expf(-fabsf(x));
  return fmaxf(x, 0.f) + __logf(1.f + z);
}

__device__ __forceinline__ float tanh_hw(float x) {
  float e = __expf(2.f * x);  // inf-safe
  return 1.f - 2.f * __builtin_amdgcn_rcpf(e + 1.f);
}

#define AWRITE(dst, src) \
  asm volatile("v_accvgpr_write_b32 %0, %1" : "=a"(dst) : "v"(src))
#define AREAD(dst, src) \
  asm volatile("v_accvgpr_read_b32 %0, %1" : "=v"(dst) : "a"(src))

__global__ __attribute__((amdgpu_waves_per_eu(2, 2)))
__launch_bounds__(512, 1) void cde_main(
    const float* __restrict__ xs,
    const float* __restrict__ icw0, const float* __restrict__ icb0,
    const float* __restrict__ icw1, const float* __restrict__ icb1,
    const float* __restrict__ icw2, const float* __restrict__ icb2,
    const float* __restrict__ vfw0, const float* __restrict__ vfb0,
    const float* __restrict__ vfw1, const float* __restrict__ vfb1,
    const float* __restrict__ vfw2, const float* __restrict__ vfb2,
    float* __restrict__ ybuf) {
  constexpr float Ac[6][5] = {
      {0.f, 0.f, 0.f, 0.f, 0.f},
      {0.161f, 0.f, 0.f, 0.f, 0.f},
      {-0.008480655492356989f, 0.335480655492357f, 0.f, 0.f, 0.f},
      {2.8971530571054935f, -6.359448489975075f, 4.3622954328695815f, 0.f, 0.f},
      {5.325864828439257f, -11.748883564062828f, 7.4955393428898365f,
       -0.09249506636175525f, 0.f},
      {5.86145544294642f, -12.92096931784711f, 8.159367898576159f,
       -0.071584973281401f, -0.028269050394068383f}};
  constexpr float SCv[6] = {0.f, 0.161f, 0.327f, 0.9f, 0.9800255409045097f, 1.f};
  constexpr float BWv[6] = {0.09646076681806523f, 0.01f, 0.4798896504144996f,
                            1.379008574103742f, -3.290069515436081f,
                            2.324710524099774f};

  const int tid = threadIdx.x;
  const int w = tid >> 6, l = tid & 63;
  const int b = blockIdx.x;  // one block per batch element

  __shared__ float sW0[128 * 68];               // W0, row stride 68 (pad)
  __shared__ float sW1[128 * 132];              // W1, row stride 132 (pad)
  __shared__ __align__(16) float sYtw[8][64];   // wave-private stage inputs
  __shared__ __align__(16) float sH1[128];
  __shared__ __align__(16) float sH2[128];
  __shared__ float sK[6][64];

  // ---- one-time: W0/W1 into LDS ----
  for (int i = tid; i < 8192; i += 512) sW0[(i >> 6) * 68 + (i & 63)] = vfw0[i];
  for (int i = tid; i < 16384; i += 512)
    sW1[(i >> 7) * 132 + (i & 127)] = vfw1[i];

  // ---- one-time: W2 rows 2tid,2tid+1 (all 128 cols) -> 256 AGPRs ----
  const int r0 = tid * 2, r1 = r0 + 1;
  float w2r0[128], w2r1[128];
  {
    const float4v* p0 = (const float4v*)(vfw2 + (size_t)r0 * 128);
    const float4v* p1 = (const float4v*)(vfw2 + (size_t)r1 * 128);
#pragma unroll
    for (int c4 = 0; c4 < 32; ++c4) {
      float4v a = p0[c4], c = p1[c4];
      w2r0[4 * c4 + 0] = a.x; w2r0[4 * c4 + 1] = a.y;
      w2r0[4 * c4 + 2] = a.z; w2r0[4 * c4 + 3] = a.w;
      w2r1[4 * c4 + 0] = c.x; w2r1[4 * c4 + 1] = c.y;
      w2r1[4 * c4 + 2] = c.z; w2r1[4 * c4 + 3] = c.w;
    }
  }
#pragma unroll
  for (int c = 0; c < 128; ++c) {
    AWRITE(w2r0[c], w2r0[c]);
    AWRITE(w2r1[c], w2r1[c]);
  }

  const float b2r0 = vfb2[r0], b2r1 = vfb2[r1];
  const int c0 = (2 * l) & 15;  // even dx channel of row r0; r1 -> c0+1
  const int ii = tid >> 2, q4 = tid & 3;  // h1/h2: 4 lanes per output
  const float b0i = vfb0[ii], b1i = vfb1[ii];

  const float* Xb = xs + (size_t)b * 4096;
  float* yb = ybuf + (size_t)b * 16384;

  __syncthreads();

  // ---- initial condition MLP (one-time; sTA := sK[0..1], sTB := sH1) ----
  float* sTA = &sK[0][0];
  float* sTB = sH1;
  if (tid < 128) {
    float a = icb0[tid];
    const float* wr = icw0 + tid * 16;
#pragma unroll
    for (int k = 0; k < 16; ++k) a += wr[k] * Xb[k];
    sTA[tid] = softplus_fast(a);
  }
  __syncthreads();
  if (tid < 128) {
    float a = icb1[tid];
    const float* wr = icw1 + tid * 128;
    for (int k = 0; k < 128; ++k) a += wr[k] * sTA[k];
    sTB[tid] = softplus_fast(a);
  }
  __syncthreads();
  if (tid < 64) {
    float a = icb2[tid];
    const float* wr = icw2 + tid * 128;
    for (int k = 0; k < 128; ++k) a += wr[k] * sTB[k];
    sH2[tid] = a;  // temp broadcast slot
  }
  __syncthreads();
  float yreg = sH2[l];  // every wave holds y[l]
  if (w == 0) yb[l] = yreg;

  const float hstep = 1.f / 255.f;
  const float invh = 255.f;

#pragma unroll 1
  for (int t = 0; t < 255; ++t) {
    // per-lane x-channel pair (c0, c0+1): j-invariant dXdt basis in regs
    float2v xt = *(const float2v*)(Xb + t * 16 + c0);
    float2v xt1 = *(const float2v*)(Xb + (t + 1) * 16 + c0);
    float2v xtm = xt;
    if (t != 0) xtm = *(const float2v*)(Xb + (t - 1) * 16 + c0);
    const float u0 = xt.x - xt1.x, u1 = xt.y - xt1.y;       // (xi - xip1)
    const float dp0 = (xt1.x - xt.x) * invh;                 // dfull[t+1]
    const float dp1 = (xt1.y - xt.y) * invh;
    float di0 = (t == 0) ? dp0 : (xt.x - xtm.x) * invh;      // dfull[t]
    float di1 = (t == 0) ? dp1 : (xt.y - xtm.y) * invh;
#pragma unroll 1
    for (int j = 0; j < 6; ++j) {
      // ---- stage input y_j: every wave, per-lane, wave-private buffer ----
      {
        float yt = yreg;
#pragma unroll
        for (int m = 0; m < 5; ++m)
          if (m < j) yt += hstep * Ac[j][m] * sK[m][l];
        sYtw[w][l] = yt;
      }
      asm volatile("s_waitcnt lgkmcnt(0)" ::: "memory");  // in-wave only
      // ---- dXdt(sc_j) in registers ----
      const float sc = SCv[j], s2 = sc * sc;
      const float a1 = (6.f * s2 - 6.f * sc) * invh;
      const float a2 = 3.f * s2 - 4.f * sc + 1.f;
      const float a3 = 3.f * s2 - 2.f * sc;
      const float dx0 = a1 * u0 + a2 * di0 + a3 * dp0;
      const float dx1 = a1 * u1 + a2 * di1 + a3 * dp1;
      // ---- h1 = softplus(W0 @ y + b0): W0 from LDS ----
      {
        const float4v* wr = (const float4v*)(sW0 + ii * 68 + q4 * 16);
        const float4v* yv = (const float4v*)(&sYtw[w][0] + q4 * 16);
        float s = dot4(wr[0], yv[0]) + dot4(wr[1], yv[1]) +
                  dot4(wr[2], yv[2]) + dot4(wr[3], yv[3]);
        s += __shfl_xor(s, 1);
        s += __shfl_xor(s, 2);
        if (q4 == 0) sH1[ii] = softplus_fast(s + b0i);
      }
      __syncthreads();
      // ---- h2 = softplus(W1 @ h1 + b1): W1 from LDS ----
      {
        const float4v* wr = (const float4v*)(sW1 + ii * 132 + q4 * 32);
        const float4v* hv = (const float4v*)(sH1 + q4 * 32);
        float s = 0.f;
#pragma unroll
        for (int kk = 0; kk < 8; ++kk) s += dot4(wr[kk], hv[kk]);
        s += __shfl_xor(s, 1);
        s += __shfl_xor(s, 2);
        if (q4 == 0) sH2[ii] = softplus_fast(s + b1i);
      }
      __syncthreads();
      // ---- k: rows r0,r1 of A = tanh(W2 h2 + b2), * dx, reduce over c ----
      {
        const float4v* hv = (const float4v*)sH2;
        float s0a = 0.f, s0b = 0.f, s1a = 0.f, s1b = 0.f;
#pragma unroll
        for (int c4 = 0; c4 < 32; ++c4) {
          float4v hk = hv[c4];
          float wa0, wa1, wa2, wa3, wb0, wb1, wb2, wb3;
          AREAD(wa0, w2r0[4 * c4 + 0]);
          AREAD(wa1, w2r0[4 * c4 + 1]);
          AREAD(wa2, w2r0[4 * c4 + 2]);
          AREAD(wa3, w2r0[4 * c4 + 3]);
          AREAD(wb0, w2r1[4 * c4 + 0]);
          AREAD(wb1, w2r1[4 * c4 + 1]);
          AREAD(wb2, w2r1[4 * c4 + 2]);
          AREAD(wb3, w2r1[4 * c4 + 3]);
          s0a += wa0 * hk.x + wa2 * hk.z;
          s0b += wa1 * hk.y + wa3 * hk.w;
          s1a += wb0 * hk.x + wb2 * hk.z;
          s1b += wb1 * hk.y + wb3 * hk.w;
        }
        float s0 = s0a + s0b, s1 = s1a + s1b;
        float f = tanh_hw(s0 + b2r0) * dx0 + tanh_hw(s1 + b2r1) * dx1;
        f += __shfl_xor(f, 1);
        f += __shfl_xor(f, 2);
        f += __shfl_xor(f, 4);
        if ((tid & 7) == 0) sK[j][tid >> 3] = f;
      }
      __syncthreads();
    }
    // ---- y_{t+1}: every wave redundantly; wave0 dumps the state ----
    {
      float yn = yreg;
#pragma unroll
      for (int m = 0; m < 6; ++m) yn += hstep * BWv[m] * sK[m][l];
      yreg = yn;
      if (w == 0) yb[(size_t)(t + 1) * 64 + l] = yn;
    }
  }
}

// Parallel readout: one thread per (b,t): out6 = y @ ro^T + rob, 6D->SO(3).
__global__ __launch_bounds__(256) void readout(
    const float* __restrict__ ybuf, const float* __restrict__ row,
    const float* __restrict__ rob, float* __restrict__ out) {
  int idx = blockIdx.x * blockDim.x + threadIdx.x;  // b*256+t
  const float* y = ybuf + (size_t)idx * 64;
  float p[6];
#pragma unroll
  for (int o = 0; o < 6; ++o) {
    const float4v* rr = (const float4v*)(row + o * 64);
    const float4v* yv = (const float4v*)y;
    float s = 0.f;
#pragma unroll
    for (int k = 0; k < 16; ++k) s += dot4(rr[k], yv[k]);
    p[o] = s + rob[o];
  }
  float a1x = p[0], a1y = p[1], a1z = p[2];
  float a2x = p[3], a2y = p[4], a2z = p[5];
  float n1 = rsqrtf(a1x * a1x + a1y * a1y + a1z * a1z);
  float b1x = a1x * n1, b1y = a1y * n1, b1z = a1z * n1;
  float d = b1x * a2x + b1y * a2y + b1z * a2z;
  float px = a2x - d * b1x, py = a2y - d * b1y, pz = a2z - d * b1z;
  float n2 = rsqrtf(px * px + py * py + pz * pz);
  float b2x = px * n2, b2y = py * n2, b2z = pz * n2;
  float b3x = b1y * b2z - b1z * b2y;
  float b3y = b1z * b2x - b1x * b2z;
  float b3z = b1x * b2y - b1y * b2x;
  float* o = out + (size_t)idx * 9;
  o[0] = b1x; o[1] = b2x; o[2] = b3x;
  o[3] = b1y; o[4] = b2y; o[5] = b3y;
  o[6] = b1z; o[7] = b2z; o[8] = b3z;
}

extern "C" void kernel_launch(void* const* d_in, const int* in_sizes, int n_in,
                              void* d_out, int out_size, void* d_ws,
                              size_t ws_size, hipStream_t stream) {
  (void)in_sizes; (void)n_in; (void)out_size; (void)ws_size;
  const float* xs   = (const float*)d_in[0];
  const float* icw0 = (const float*)d_in[1];
  const float* icb0 = (const float*)d_in[2];
  const float* icw1 = (const float*)d_in[3];
  const float* icb1 = (const float*)d_in[4];
  const float* icw2 = (const float*)d_in[5];
  const float* icb2 = (const float*)d_in[6];
  const float* vfw0 = (const float*)d_in[7];
  const float* vfb0 = (const float*)d_in[8];
  const float* vfw1 = (const float*)d_in[9];
  const float* vfb1 = (const float*)d_in[10];
  const float* vfw2 = (const float*)d_in[11];
  const float* vfb2 = (const float*)d_in[12];
  const float* row  = (const float*)d_in[13];
  const float* rob  = (const float*)d_in[14];
  float* ybuf = (float*)d_ws;  // 64*256*64 floats = 4 MB

  hipLaunchKernelGGL(cde_main, dim3(64), dim3(512), 0, stream,
                     xs, icw0, icb0, icw1, icb1, icw2, icb2,
                     vfw0, vfb0, vfw1, vfb1, vfw2, vfb2, ybuf);
  hipLaunchKernelGGL(readout, dim3(64), dim3(256), 0, stream,
                     ybuf, row, rob, (float*)d_out);
}

// Round 14
// 10625.883 us; speedup vs baseline: 1.2588x; 1.2588x over previous
//
#include <hip/hip_runtime.h>

// NeuralCDE: B=64,T=256,C=16,S=64,H=128. fp32 recursion (f16 decorrelates).
// R12 6.52ms = structural floor of 1-CU-per-batch: >=450KB/stage must cross
// the per-CU L2 port (~135GB/s) since weights (608KB) >> LDS (160KB).
// R13 AGPR residency: worked but 2 VALU/MAC -> 13.4ms. Pivot:
// R14: 4 CUs per batch (256 blocks, 1/CU by LDS). Block p owns W2 rows
// 256p..256p+255 FULLY LDS-RESIDENT (128KB col-major). W0/W1 streamed
// (96KB/stage, only L2 bulk). k-slice exchange is FENCE-FREE: value+tag
// packed in one 8B word, relaxed agent-scope atomics (no L2 wb/inv — R5's
// 62ms failure was the fences, not the exchange). Depth-2 slots; 0xAA poison
// never matches tags 1..1530 (no init); same-XCD placement (members differ
// by 64 = 0 mod 8); guarded spin turns co-residency failure into fast-fail.
// k in per-lane regs (no sK LDS); 2 barriers/stage.

typedef float float4v __attribute__((ext_vector_type(4)));
typedef float float2v __attribute__((ext_vector_type(2)));

__device__ __forceinline__ float dot4(float4v a, float4v b) {
  return a.x * b.x + a.y * b.y + a.z * b.z + a.w * b.w;
}

__device__ __forceinline__ float softplus_fast(float x) {
  float z = __expf(-fabsf(x));
  return fmaxf(x, 0.f) + __logf(1.f + z);
}

__device__ __forceinline__ float tanh_hw(float x) {
  float e = __expf(2.f * x);  // inf-safe
  return 1.f - 2.f * __builtin_amdgcn_rcpf(e + 1.f);
}

__device__ __forceinline__ float kwait(const unsigned long long* p,
                                       unsigned tag, bool& dead) {
  unsigned long long v =
      __hip_atomic_load(p, __ATOMIC_RELAXED, __HIP_MEMORY_SCOPE_AGENT);
  if (dead) return __uint_as_float((unsigned)v);
  int guard = 0;
  while ((unsigned)(v >> 32) != tag) {
    if (++guard > (1 << 22)) { dead = true; break; }
    __builtin_amdgcn_s_sleep(1);
    v = __hip_atomic_load(p, __ATOMIC_RELAXED, __HIP_MEMORY_SCOPE_AGENT);
  }
  return __uint_as_float((unsigned)v);
}

__global__ __launch_bounds__(512, 1) void cde_main(
    const float* __restrict__ xs,
    const float* __restrict__ icw0, const float* __restrict__ icb0,
    const float* __restrict__ icw1, const float* __restrict__ icb1,
    const float* __restrict__ icw2, const float* __restrict__ icb2,
    const float* __restrict__ vfw0, const float* __restrict__ vfb0,
    const float* __restrict__ vfw1, const float* __restrict__ vfb1,
    const float* __restrict__ vfw2, const float* __restrict__ vfb2,
    unsigned long long* __restrict__ kbuf, float* __restrict__ ybuf) {
  constexpr float Ac[6][5] = {
      {0.f, 0.f, 0.f, 0.f, 0.f},
      {0.161f, 0.f, 0.f, 0.f, 0.f},
      {-0.008480655492356989f, 0.335480655492357f, 0.f, 0.f, 0.f},
      {2.8971530571054935f, -6.359448489975075f, 4.3622954328695815f, 0.f, 0.f},
      {5.325864828439257f, -11.748883564062828f, 7.4955393428898365f,
       -0.09249506636175525f, 0.f},
      {5.86145544294642f, -12.92096931784711f, 8.159367898576159f,
       -0.071584973281401f, -0.028269050394068383f}};
  constexpr float SCv[6] = {0.f, 0.161f, 0.327f, 0.9f, 0.9800255409045097f, 1.f};
  constexpr float BWv[6] = {0.09646076681806523f, 0.01f, 0.4798896504144996f,
                            1.379008574103742f, -3.290069515436081f,
                            2.324710524099774f};

  const int tid = threadIdx.x;
  const int w = tid >> 6, l = tid & 63;
  const int batch = blockIdx.x & 63;  // group members differ by 64 -> same XCD
  const int p = blockIdx.x >> 6;      // W2 row-slice owner (0..3)

  __shared__ float sW2[128 * 256];            // slice rows, col-major [c][r]
  __shared__ __align__(16) float sYtw[8][64]; // wave-private stage inputs
  __shared__ __align__(16) float sH1[128];
  __shared__ __align__(16) float sH2[128];
  __shared__ __align__(16) float sY0[64];

  // ---- one-time: W2 slice into LDS, col-major ----
  for (int i = tid; i < 32768; i += 512) {
    int r = i & 255, c = i >> 8;
    sW2[c * 256 + r] = vfw2[(size_t)(256 * p + r) * 128 + c];
  }

  // roles
  const int q2 = l & 3;                 // A-phase col quarter
  const int pg = w * 16 + (l >> 2);     // local row pair 0..127
  const int r0 = 2 * pg, r1 = r0 + 1;   // local rows in slice
  const int c0 = r0 & 15;               // dx channels c0, c0+1
  const float b2r0 = vfb2[256 * p + r0], b2r1 = vfb2[256 * p + r1];
  const int sidx = p * 16 + (r0 >> 4);  // s written by lanes l==0, l==32
  const int ii = tid >> 2, q4 = tid & 3;
  const float b0i = vfb0[ii], b1i = vfb1[ii];

  const float* Xb = xs + (size_t)batch * 4096;
  unsigned long long* kb = kbuf + (size_t)batch * 128;  // 2 slots x 64
  float* yb = ybuf + (size_t)batch * 16384;

  __syncthreads();

  // ---- initial condition MLP (redundant per block, deterministic) ----
  if (tid < 128) {
    float a = icb0[tid];
    const float* wr = icw0 + tid * 16;
#pragma unroll
    for (int k = 0; k < 16; ++k) a += wr[k] * Xb[k];
    sH1[tid] = softplus_fast(a);
  }
  __syncthreads();
  if (tid < 128) {
    float a = icb1[tid];
    const float* wr = icw1 + tid * 128;
    for (int k = 0; k < 128; ++k) a += wr[k] * sH1[k];
    sH2[tid] = softplus_fast(a);
  }
  __syncthreads();
  if (tid < 64) {
    float a = icb2[tid];
    const float* wr = icw2 + tid * 128;
    for (int k = 0; k < 128; ++k) a += wr[k] * sH2[k];
    sY0[tid] = a;
  }
  __syncthreads();
  float yreg = sY0[l];  // every wave holds y[l]
  if (p == 0 && w == 0) yb[l] = yreg;
  float kreg[6];
  bool dead = false;

  const float hstep = 1.f / 255.f;
  const float invh = 255.f;

#pragma unroll 1
  for (int t = 0; t < 255; ++t) {
    // per-lane dXdt basis for channels (c0, c0+1)
    float2v xt = *(const float2v*)(Xb + t * 16 + c0);
    float2v xt1 = *(const float2v*)(Xb + (t + 1) * 16 + c0);
    float2v xtm = xt;
    if (t != 0) xtm = *(const float2v*)(Xb + (t - 1) * 16 + c0);
    const float u0 = xt.x - xt1.x, u1 = xt.y - xt1.y;
    const float dp0 = (xt1.x - xt.x) * invh;
    const float dp1 = (xt1.y - xt.y) * invh;
    const float di0 = (t == 0) ? dp0 : (xt.x - xtm.x) * invh;
    const float di1 = (t == 0) ? dp1 : (xt.y - xtm.y) * invh;
#pragma unroll 1
    for (int j = 0; j < 6; ++j) {
      const int g = t * 6 + j;
      const unsigned tag = (unsigned)(g + 1);
      unsigned long long* slot = kb + (g & 1) * 64;
      // ---- streamed W0/W1 rows (only per-stage L2 traffic: 96KB/CU) ----
      const float4v* w0p = (const float4v*)(vfw0 + (size_t)ii * 64 + q4 * 16);
      const float4v* w1p = (const float4v*)(vfw1 + (size_t)ii * 128 + q4 * 32);
      float4v w0r[4];
#pragma unroll
      for (int kk = 0; kk < 4; ++kk) w0r[kk] = w0p[kk];
      float4v w1r[8];
#pragma unroll
      for (int kk = 0; kk < 8; ++kk) w1r[kk] = w1p[kk];
      // ---- stage input y_j: per-wave private buffer, in-wave wait only ----
      {
        float yt = yreg;
#pragma unroll
        for (int m = 0; m < 5; ++m)
          if (m < j) yt += hstep * Ac[j][m] * kreg[m];
        sYtw[w][l] = yt;
      }
      asm volatile("s_waitcnt lgkmcnt(0)" ::: "memory");
      // ---- dXdt(sc_j) in registers ----
      const float sc = SCv[j], s2 = sc * sc;
      const float a1 = (6.f * s2 - 6.f * sc) * invh;
      const float a2 = 3.f * s2 - 4.f * sc + 1.f;
      const float a3 = 3.f * s2 - 2.f * sc;
      const float dx0 = a1 * u0 + a2 * di0 + a3 * dp0;
      const float dx1 = a1 * u1 + a2 * di1 + a3 * dp1;
      // ---- h1 = softplus(W0 @ y + b0) ----
      {
        const float4v* yv = (const float4v*)(&sYtw[w][0] + q4 * 16);
        float s = dot4(w0r[0], yv[0]) + dot4(w0r[1], yv[1]) +
                  dot4(w0r[2], yv[2]) + dot4(w0r[3], yv[3]);
        s += __shfl_xor(s, 1);
        s += __shfl_xor(s, 2);
        if (q4 == 0) sH1[ii] = softplus_fast(s + b0i);
      }
      __syncthreads();
      // ---- h2 = softplus(W1 @ h1 + b1) ----
      {
        const float4v* hv = (const float4v*)(sH1 + q4 * 32);
        float s = 0.f;
#pragma unroll
        for (int kk = 0; kk < 8; ++kk) s += dot4(w1r[kk], hv[kk]);
        s += __shfl_xor(s, 1);
        s += __shfl_xor(s, 2);
        if (q4 == 0) sH2[ii] = softplus_fast(s + b1i);
      }
      __syncthreads();
      // ---- A-slice: rows r0,r1 x cols q2*32..+31 from LDS ----
      {
        const float4v* h2v = (const float4v*)(sH2 + q2 * 32);
        float s0 = 0.f, s1 = 0.f;
#pragma unroll
        for (int cc4 = 0; cc4 < 8; ++cc4) {
          float4v h = h2v[cc4];
          const float* base = sW2 + (q2 * 32 + cc4 * 4) * 256 + r0;
          float2v wp0 = *(const float2v*)(base);
          float2v wp1 = *(const float2v*)(base + 256);
          float2v wp2 = *(const float2v*)(base + 512);
          float2v wp3 = *(const float2v*)(base + 768);
          s0 += wp0.x * h.x + wp1.x * h.y + wp2.x * h.z + wp3.x * h.w;
          s1 += wp0.y * h.x + wp1.y * h.y + wp2.y * h.z + wp3.y * h.w;
        }
        s0 += __shfl_xor(s0, 1);
        s0 += __shfl_xor(s0, 2);
        s1 += __shfl_xor(s1, 1);
        s1 += __shfl_xor(s1, 2);
        float f = tanh_hw(s0 + b2r0) * dx0 + tanh_hw(s1 + b2r1) * dx1;
        f += __shfl_xor(f, 4);
        f += __shfl_xor(f, 8);
        f += __shfl_xor(f, 16);  // sums the 8 pairs (bits 2..4); quad copies
                                 // (bits 0,1) and half (bit 5) untouched -> k_s
        if ((l & 31) == 0) {
          unsigned long long pv =
              ((unsigned long long)tag << 32) | __float_as_uint(f);
          __hip_atomic_store(slot + sidx, pv, __ATOMIC_RELAXED,
                             __HIP_MEMORY_SCOPE_AGENT);
        }
      }
      // ---- fence-free gather: every thread spins on its lane word ----
      kreg[j] = kwait(slot + l, tag, dead);
    }
    // ---- y_{t+1} (every wave redundantly); p0/w0 dumps the state ----
    {
      float yn = yreg;
#pragma unroll
      for (int m = 0; m < 6; ++m) yn += hstep * BWv[m] * kreg[m];
      yreg = yn;
      if (p == 0 && w == 0) yb[(size_t)(t + 1) * 64 + l] = yn;
    }
  }
}

// Parallel readout: one thread per (b,t): out6 = y @ ro^T + rob, 6D->SO(3).
__global__ __launch_bounds__(256) void readout(
    const float* __restrict__ ybuf, const float* __restrict__ row,
    const float* __restrict__ rob, float* __restrict__ out) {
  int idx = blockIdx.x * blockDim.x + threadIdx.x;  // b*256+t
  const float* y = ybuf + (size_t)idx * 64;
  float p[6];
#pragma unroll
  for (int o = 0; o < 6; ++o) {
    const float4v* rr = (const float4v*)(row + o * 64);
    const float4v* yv = (const float4v*)y;
    float s = 0.f;
#pragma unroll
    for (int k = 0; k < 16; ++k) s += dot4(rr[k], yv[k]);
    p[o] = s + rob[o];
  }
  float a1x = p[0], a1y = p[1], a1z = p[2];
  float a2x = p[3], a2y = p[4], a2z = p[5];
  float n1 = rsqrtf(a1x * a1x + a1y * a1y + a1z * a1z);
  float b1x = a1x * n1, b1y = a1y * n1, b1z = a1z * n1;
  float d = b1x * a2x + b1y * a2y + b1z * a2z;
  float px = a2x - d * b1x, py = a2y - d * b1y, pz = a2z - d * b1z;
  float n2 = rsqrtf(px * px + py * py + pz * pz);
  float b2x = px * n2, b2y = py * n2, b2z = pz * n2;
  float b3x = b1y * b2z - b1z * b2y;
  float b3y = b1z * b2x - b1x * b2z;
  float b3z = b1x * b2y - b1y * b2x;
  float* o = out + (size_t)idx * 9;
  o[0] = b1x; o[1] = b2x; o[2] = b3x;
  o[3] = b1y; o[4] = b2y; o[5] = b3y;
  o[6] = b1z; o[7] = b2z; o[8] = b3z;
}

extern "C" void kernel_launch(void* const* d_in, const int* in_sizes, int n_in,
                              void* d_out, int out_size, void* d_ws,
                              size_t ws_size, hipStream_t stream) {
  (void)in_sizes; (void)n_in; (void)out_size; (void)ws_size;
  const float* xs   = (const float*)d_in[0];
  const float* icw0 = (const float*)d_in[1];
  const float* icb0 = (const float*)d_in[2];
  const float* icw1 = (const float*)d_in[3];
  const float* icb1 = (const float*)d_in[4];
  const float* icw2 = (const float*)d_in[5];
  const float* icb2 = (const float*)d_in[6];
  const float* vfw0 = (const float*)d_in[7];
  const float* vfb0 = (const float*)d_in[8];
  const float* vfw1 = (const float*)d_in[9];
  const float* vfb1 = (const float*)d_in[10];
  const float* vfw2 = (const float*)d_in[11];
  const float* vfb2 = (const float*)d_in[12];
  const float* row  = (const float*)d_in[13];
  const float* rob  = (const float*)d_in[14];

  unsigned long long* kbuf = (unsigned long long*)d_ws;  // 64*2*64*8B = 64KB
  float* ybuf = (float*)((char*)d_ws + 65536);           // 4MB

  hipLaunchKernelGGL(cde_main, dim3(256), dim3(512), 0, stream,
                     xs, icw0, icb0, icw1, icb1, icw2, icb2,
                     vfw0, vfb0, vfw1, vfb1, vfw2, vfb2, kbuf, ybuf);
  hipLaunchKernelGGL(readout, dim3(64), dim3(256), 0, stream,
                     ybuf, row, rob, (float*)d_out);
}